// Round 3
// baseline (866.901 us; speedup 1.0000x reference)
//
#include <hip/hip_runtime.h>
#include <hip/hip_bf16.h>

typedef __attribute__((ext_vector_type(8))) __bf16 bf16x8;
typedef __attribute__((ext_vector_type(4))) float f32x4;
typedef __attribute__((ext_vector_type(4))) unsigned short us4;

__device__ __forceinline__ unsigned short f2bf(float f){
  union { float f; unsigned int u; } a; a.f = f;
  unsigned int r = 0x7fffu + ((a.u >> 16) & 1u);
  return (unsigned short)((a.u + r) >> 16);
}

__device__ __forceinline__ void gload_lds16(const unsigned short* g, void* l){
  __builtin_amdgcn_global_load_lds(
      (const __attribute__((address_space(1))) void*)g,
      (__attribute__((address_space(3))) void*)l, 16, 0, 0);
}

// ---------------- cast fp32 -> bf16 (vector4) ----------------
__global__ __launch_bounds__(256) void cast_kernel(const float* __restrict__ in,
                                                   unsigned short* __restrict__ out, int n4){
  int i = blockIdx.x * 256 + threadIdx.x;
  if (i >= n4) return;
  float4 v = ((const float4*)in)[i];
  us4 o; o.x = f2bf(v.x); o.y = f2bf(v.y); o.z = f2bf(v.z); o.w = f2bf(v.w);
  ((us4*)out)[i] = o;
}

// ---------------- modulation: y = silu(emb) @ w.T (3 matrices of 3072x1024) ----------------
__global__ __launch_bounds__(256) void modulation_kernel(const float* __restrict__ emb,
    const float* __restrict__ w0, const float* __restrict__ w1, const float* __restrict__ w2,
    float* __restrict__ out){
  int gw = blockIdx.x * 4 + (threadIdx.x >> 6);
  int lane = threadIdx.x & 63;
  int mat = gw / 3072, row = gw % 3072;
  const float* w = (mat == 0) ? w0 : (mat == 1 ? w1 : w2);
  float acc = 0.f;
  for (int i = lane; i < 1024; i += 64){
    float e = emb[i];
    float s = e / (1.f + expf(-e));
    acc += s * w[row * 1024 + i];
  }
  #pragma unroll
  for (int m = 32; m >= 1; m >>= 1) acc += __shfl_xor(acc, m, 64);
  if (lane == 0) out[mat * 3072 + row] = acc;
}

// ---------------- layernorm * (1+scale) + shift -> bf16 ----------------
__global__ __launch_bounds__(256) void ln_mod_kernel(const float* __restrict__ x,
    const float* __restrict__ mod, unsigned short* __restrict__ h){
  int row = blockIdx.x, t = threadIdx.x;
  const float* xr = x + (size_t)row * 1024;
  float4 v = ((const float4*)xr)[t];
  float s = v.x + v.y + v.z + v.w;
  #pragma unroll
  for (int m = 32; m >= 1; m >>= 1) s += __shfl_xor(s, m, 64);
  __shared__ float red[4], red2[4];
  int wid = t >> 6, lane = t & 63;
  if (lane == 0) red[wid] = s;
  __syncthreads();
  float mean = (red[0] + red[1] + red[2] + red[3]) * (1.f / 1024.f);
  float dx = v.x - mean, dy = v.y - mean, dz = v.z - mean, dw = v.w - mean;
  float s2 = dx*dx + dy*dy + dz*dz + dw*dw;
  #pragma unroll
  for (int m = 32; m >= 1; m >>= 1) s2 += __shfl_xor(s2, m, 64);
  if (lane == 0) red2[wid] = s2;
  __syncthreads();
  float var = (red2[0] + red2[1] + red2[2] + red2[3]) * (1.f / 1024.f);
  float rs = rsqrtf(var + 1e-6f);
  int c = t * 4;
  us4 o;
  o.x = f2bf(dx * rs * (1.f + mod[1024 + c    ]) + mod[c    ]);
  o.y = f2bf(dy * rs * (1.f + mod[1024 + c + 1]) + mod[c + 1]);
  o.z = f2bf(dz * rs * (1.f + mod[1024 + c + 2]) + mod[c + 2]);
  o.w = f2bf(dw * rs * (1.f + mod[1024 + c + 3]) + mod[c + 3]);
  ((us4*)(h + (size_t)row * 1024))[t] = o;
}

// ---------------- rmsnorm (*nw) + optional rope, fp32 [S][16][64] -> bf16 [16][S][64] ----------------
template<int ROPE>
__global__ __launch_bounds__(256) void qk_post_kernel(const float* __restrict__ qin,
    const float* __restrict__ nw, const float* __restrict__ rope,
    unsigned short* __restrict__ qout, int S){
  int gw = blockIdx.x * 4 + (threadIdx.x >> 6);
  int lane = threadIdx.x & 63;
  int s = gw >> 4, h = gw & 15;
  float v = qin[(size_t)s * 1024 + h * 64 + lane];
  float ss = v * v;
  #pragma unroll
  for (int m = 32; m >= 1; m >>= 1) ss += __shfl_xor(ss, m, 64);
  float val = v * rsqrtf(ss * (1.f / 64.f) + 1e-6f) * nw[lane];
  if (ROPE){
    float partner = __shfl_xor(val, 32, 64);
    float cs = rope[s * 64 + (lane & 31)];
    float sn = rope[s * 64 + 32 + (lane & 31)];
    val = (lane < 32) ? (val * cs - partner * sn) : (val * cs + partner * sn);
  }
  qout[((size_t)h * S + s) * 64 + lane] = f2bf(val);
}

// ---------------- V transpose: fp32 [S][16][64] -> bf16 [16][64][S] ----------------
__global__ __launch_bounds__(256) void vt_kernel(const float* __restrict__ Vf,
    unsigned short* __restrict__ Vt, int S){
  int stile = blockIdx.x, h = blockIdx.y;
  __shared__ unsigned short tile[64 * 66];
  int t = threadIdx.x;
  #pragma unroll
  for (int i = 0; i < 16; i++){
    int e = i * 256 + t;
    int srow = e >> 6, d = e & 63;
    tile[d * 66 + srow] = f2bf(Vf[(size_t)(stile * 64 + srow) * 1024 + h * 64 + d]);
  }
  __syncthreads();
  #pragma unroll
  for (int i = 0; i < 16; i++){
    int e = i * 256 + t;
    int d = e >> 6, scol = e & 63;
    Vt[((size_t)h * 64 + d) * S + stile * 64 + scol] = tile[d * 66 + scol];
  }
}

// ---------------- GEMM: C[M,N] = A[M,K](bf16) * W[N,K](bf16)^T, fp32 acc ----------------
template<int EPI>
__global__ __launch_bounds__(256) void gemm_bt_kernel(
    const unsigned short* __restrict__ A, const unsigned short* __restrict__ W,
    int M, int N, int K,
    float* __restrict__ outF, unsigned short* __restrict__ outB,
    const float* __restrict__ resid, const float* __restrict__ gate){
  __shared__ short As[128 * 64];
  __shared__ short Bs[128 * 64];
  const int t = threadIdx.x, wid = t >> 6, lane = t & 63;
  const int r = lane & 15, g = lane >> 4;
  const int brow = blockIdx.y * 128, bcol = blockIdx.x * 128;
  const int wr = wid >> 1, wc = wid & 1;
  f32x4 acc[4][4] = {};
  const int nkt = K >> 6;
  for (int kt = 0; kt < nkt; ++kt){
    const int k0 = kt << 6;
    #pragma unroll
    for (int i = 0; i < 4; i++){
      int chunk = wid * 4 + i;
      int rowi = chunk * 8 + (lane >> 3);
      int lce = ((lane & 7) * 8) ^ ((rowi & 7) << 3);
      gload_lds16(A + (size_t)(brow + rowi) * K + k0 + lce, (void*)(As + chunk * 512));
      gload_lds16(W + (size_t)(bcol + rowi) * K + k0 + lce, (void*)(Bs + chunk * 512));
    }
    __syncthreads();
    #pragma unroll
    for (int kk = 0; kk < 2; kk++){
      bf16x8 af[4], bfr[4];
      #pragma unroll
      for (int m = 0; m < 4; m++){
        int ar = wr * 64 + m * 16 + r;
        af[m] = *(const bf16x8*)(As + ar * 64 + ((kk * 32 + g * 8) ^ ((ar & 7) << 3)));
      }
      #pragma unroll
      for (int n = 0; n < 4; n++){
        int br = wc * 64 + n * 16 + r;
        bfr[n] = *(const bf16x8*)(Bs + br * 64 + ((kk * 32 + g * 8) ^ ((br & 7) << 3)));
      }
      #pragma unroll
      for (int m = 0; m < 4; m++)
        #pragma unroll
        for (int n = 0; n < 4; n++)
          acc[m][n] = __builtin_amdgcn_mfma_f32_16x16x32_bf16(af[m], bfr[n], acc[m][n], 0, 0, 0);
    }
    __syncthreads();
  }
  #pragma unroll
  for (int m = 0; m < 4; m++){
    #pragma unroll
    for (int n = 0; n < 4; n++){
      int col = bcol + wc * 64 + n * 16 + r;
      #pragma unroll
      for (int j = 0; j < 4; j++){
        int rowj = brow + wr * 64 + m * 16 + g * 4 + j;
        float v = acc[m][n][j];
        if (EPI == 0){
          outF[(size_t)rowj * N + col] = v;
        } else if (EPI == 2){
          float gl = 0.5f * v * (1.f + erff(v * 0.70710678118654752f));
          outB[(size_t)rowj * N + col] = f2bf(gl);
        } else {
          outF[(size_t)rowj * N + col] = resid[(size_t)rowj * N + col] + gate[col] * v;
        }
      }
    }
  }
}

// ---------------- flash attention, KV-split x2 ----------------
// Q: bf16 [16][Sq][64], K: bf16 [16][Skv][64], Vt: bf16 [16][64][Skv], Out: bf16 [Sq][1024]
// 8 waves/block (512 thr): wave = (qsub 0..3) x (kv-half 0..1). 32 q-rows/wave.
// K/V fragments direct from global (L2-resident, XCD-aware head placement).
// After the loop: LDS flash-combine of the two halves (merge buffer aliases Ps).
__global__ __launch_bounds__(512, 4) void attn_kernel(
    const unsigned short* __restrict__ Qb, const unsigned short* __restrict__ Kb,
    const unsigned short* __restrict__ Vt, unsigned short* __restrict__ Out,
    int Sq, int Skv){
  __shared__ char smem[8 * 32 * 72 * 2];              // Ps (8 waves); merge region aliases it
  short* Ps = (short*)smem;
  float* mo = (float*)smem;                            // 128 rows x 64 cols f32 = 32 KB
  float* ml = (float*)(smem + 32768);                  // 128 rows x {m,l} = 1 KB
  const int t = threadIdx.x, wid = t >> 6, lane = t & 63;
  const int r = lane & 15, g = lane >> 4;
  const int qsub = wid & 3, half = wid >> 2;
  const int bid = blockIdx.x;
  const int slot = bid >> 3;
  const int h = (bid & 7) * 2 + (slot >> 5);
  const int qblk = slot & 31;
  const int qbase = qblk * 128 + qsub * 32;
  const float SC = 0.125f * 1.44269504f;               // score scale * log2(e): exp -> exp2

  bf16x8 qf[2][2];
  #pragma unroll
  for (int tile = 0; tile < 2; tile++){
    const unsigned short* qp = Qb + ((size_t)h * Sq + qbase + tile * 16 + r) * 64 + g * 8;
    qf[tile][0] = *(const bf16x8*)qp;
    qf[tile][1] = *(const bf16x8*)(qp + 32);
  }
  f32x4 o[2][4] = {};
  float mrun[2][4], lrun[2][4];
  #pragma unroll
  for (int tile = 0; tile < 2; tile++)
    #pragma unroll
    for (int j = 0; j < 4; j++){ mrun[tile][j] = -__builtin_inff(); lrun[tile][j] = 0.f; }

  const int kvHalf = Skv >> 1;
  const int kv0 = half * kvHalf;
  for (int kv = kv0; kv < kv0 + kvHalf; kv += 64){
    // ---- QK^T: K fragments direct from global ----
    const unsigned short* kp = Kb + ((size_t)h * Skv + kv + r) * 64 + g * 8;
    f32x4 sf[2][4];
    __builtin_amdgcn_s_setprio(1);
    #pragma unroll
    for (int kj = 0; kj < 4; kj++){
      bf16x8 k0 = *(const bf16x8*)(kp + kj * 1024);
      bf16x8 k1 = *(const bf16x8*)(kp + kj * 1024 + 32);
      f32x4 a0 = {}, a1 = {};
      a0 = __builtin_amdgcn_mfma_f32_16x16x32_bf16(qf[0][0], k0, a0, 0, 0, 0);
      a0 = __builtin_amdgcn_mfma_f32_16x16x32_bf16(qf[0][1], k1, a0, 0, 0, 0);
      a1 = __builtin_amdgcn_mfma_f32_16x16x32_bf16(qf[1][0], k0, a1, 0, 0, 0);
      a1 = __builtin_amdgcn_mfma_f32_16x16x32_bf16(qf[1][1], k1, a1, 0, 0, 0);
      sf[0][kj] = a0 * SC;
      sf[1][kj] = a1 * SC;
    }
    __builtin_amdgcn_s_setprio(0);
    // ---- V fragments: issue early so latency hides under softmax ----
    bf16x8 vf[2][4];
    const unsigned short* vp = Vt + ((size_t)h * 64 + r) * Skv + kv + g * 8;
    #pragma unroll
    for (int dj = 0; dj < 4; dj++){
      vf[0][dj] = *(const bf16x8*)(vp + (size_t)dj * 16 * Skv);
      vf[1][dj] = *(const bf16x8*)(vp + (size_t)dj * 16 * Skv + 32);
    }
    // ---- online softmax in exp2 domain (defer-rescale, THR=8) ----
    #pragma unroll
    for (int tile = 0; tile < 2; tile++){
      float tm[4];
      int need = 0;
      #pragma unroll
      for (int j = 0; j < 4; j++){
        float m0 = fmaxf(fmaxf(sf[tile][0][j], sf[tile][1][j]),
                         fmaxf(sf[tile][2][j], sf[tile][3][j]));
        #pragma unroll
        for (int msk = 8; msk >= 1; msk >>= 1) m0 = fmaxf(m0, __shfl_xor(m0, msk, 64));
        tm[j] = m0;
        need |= (m0 > mrun[tile][j] + 8.f) ? 1 : 0;
      }
      if (__any(need)){
        #pragma unroll
        for (int j = 0; j < 4; j++){
          float mnew = fmaxf(mrun[tile][j], tm[j]);
          float corr = exp2f(mrun[tile][j] - mnew);
          mrun[tile][j] = mnew;
          lrun[tile][j] *= corr;
          #pragma unroll
          for (int dj = 0; dj < 4; dj++) o[tile][dj][j] *= corr;
        }
      }
      #pragma unroll
      for (int j = 0; j < 4; j++){
        float rsum = 0.f;
        #pragma unroll
        for (int kj = 0; kj < 4; kj++){
          float p = exp2f(sf[tile][kj][j] - mrun[tile][j]);
          rsum += p;
          Ps[(size_t)wid * 2304 + (tile * 16 + g * 4 + j) * 72 + kj * 16 + r] = (short)f2bf(p);
        }
        #pragma unroll
        for (int msk = 8; msk >= 1; msk >>= 1) rsum += __shfl_xor(rsum, msk, 64);
        lrun[tile][j] += rsum;
      }
    }
    asm volatile("s_waitcnt lgkmcnt(0)" ::: "memory");
    // ---- PV ----
    __builtin_amdgcn_s_setprio(1);
    #pragma unroll
    for (int tile = 0; tile < 2; tile++){
      bf16x8 pf0 = *(const bf16x8*)(Ps + (size_t)wid * 2304 + (tile * 16 + r) * 72 + g * 8);
      bf16x8 pf1 = *(const bf16x8*)(Ps + (size_t)wid * 2304 + (tile * 16 + r) * 72 + 32 + g * 8);
      #pragma unroll
      for (int dj = 0; dj < 4; dj++){
        o[tile][dj] = __builtin_amdgcn_mfma_f32_16x16x32_bf16(pf0, vf[0][dj], o[tile][dj], 0, 0, 0);
        o[tile][dj] = __builtin_amdgcn_mfma_f32_16x16x32_bf16(pf1, vf[1][dj], o[tile][dj], 0, 0, 0);
      }
    }
    __builtin_amdgcn_s_setprio(0);
  }

  // ---- flash-combine the two kv halves ----
  __syncthreads();                                     // everyone done with Ps
  if (half == 1){
    #pragma unroll
    for (int tile = 0; tile < 2; tile++){
      #pragma unroll
      for (int j = 0; j < 4; j++){
        int rl = qsub * 32 + tile * 16 + g * 4 + j;
        if (r == 0){ ml[rl * 2] = mrun[tile][j]; ml[rl * 2 + 1] = lrun[tile][j]; }
        #pragma unroll
        for (int dj = 0; dj < 4; dj++) mo[rl * 64 + dj * 16 + r] = o[tile][dj][j];
      }
    }
  }
  __syncthreads();
  if (half == 0){
    #pragma unroll
    for (int tile = 0; tile < 2; tile++){
      #pragma unroll
      for (int j = 0; j < 4; j++){
        int rl = qsub * 32 + tile * 16 + g * 4 + j;
        float m1 = ml[rl * 2], l1 = ml[rl * 2 + 1];
        float m0 = mrun[tile][j], l0 = lrun[tile][j];
        float mm = fmaxf(m0, m1);
        float c0 = exp2f(m0 - mm), c1 = exp2f(m1 - mm);
        float inv = 1.f / (l0 * c0 + l1 * c1);
        int qrow = qblk * 128 + rl;
        #pragma unroll
        for (int dj = 0; dj < 4; dj++){
          float val = (o[tile][dj][j] * c0 + mo[rl * 64 + dj * 16 + r] * c1) * inv;
          Out[(size_t)qrow * 1024 + h * 64 + dj * 16 + r] = f2bf(val);
        }
      }
    }
  }
}

extern "C" void kernel_launch(void* const* d_in, const int* in_sizes, int n_in,
                              void* d_out, int out_size, void* d_ws, size_t ws_size,
                              hipStream_t stream){
  (void)n_in; (void)out_size;
  const float* x   = (const float*)d_in[0];
  const float* emb = (const float*)d_in[1];
  const float* ctx = (const float*)d_in[2];
  int wb = 3, ri = 20;
  if (in_sizes[3] == 4096 * 64) { ri = 3; wb = 4; }
  const float* rope  = (const float*)d_in[ri];
  const float* sa_wq = (const float*)d_in[wb + 0];
  const float* sa_wk = (const float*)d_in[wb + 1];
  const float* sa_wv = (const float*)d_in[wb + 2];
  const float* sa_wo = (const float*)d_in[wb + 3];
  const float* sa_qn = (const float*)d_in[wb + 4];
  const float* sa_kn = (const float*)d_in[wb + 5];
  const float* ca_wq = (const float*)d_in[wb + 6];
  const float* ca_wk = (const float*)d_in[wb + 7];
  const float* ca_wv = (const float*)d_in[wb + 8];
  const float* ca_wo = (const float*)d_in[wb + 9];
  const float* ca_qn = (const float*)d_in[wb + 10];
  const float* ca_kn = (const float*)d_in[wb + 11];
  const float* w1    = (const float*)d_in[wb + 12];
  const float* w2    = (const float*)d_in[wb + 13];
  const float* msa   = (const float*)d_in[wb + 14];
  const float* mca   = (const float*)d_in[wb + 15];
  const float* mmlp  = (const float*)d_in[wb + 16];

  char* ws = (char*)d_ws;
  const size_t MB = 1u << 20;
  if (ws_size < 114 * MB) return;
  unsigned short* wq_sa = (unsigned short*)(ws + 0 * MB);
  unsigned short* wk_sa = (unsigned short*)(ws + 2 * MB);
  unsigned short* wv_sa = (unsigned short*)(ws + 4 * MB);
  unsigned short* wo_sa = (unsigned short*)(ws + 6 * MB);
  unsigned short* wq_ca = (unsigned short*)(ws + 8 * MB);
  unsigned short* wk_ca = (unsigned short*)(ws + 10 * MB);
  unsigned short* wv_ca = (unsigned short*)(ws + 12 * MB);
  unsigned short* wo_ca = (unsigned short*)(ws + 14 * MB);
  unsigned short* w1bf  = (unsigned short*)(ws + 16 * MB);
  unsigned short* w2bf  = (unsigned short*)(ws + 24 * MB);
  unsigned short* ctxbf = (unsigned short*)(ws + 32 * MB);
  float*          modv  = (float*)(ws + 33 * MB);
  unsigned short* hbf   = (unsigned short*)(ws + 34 * MB);
  unsigned short* qbf   = (unsigned short*)(ws + 42 * MB);
  unsigned short* kbf   = (unsigned short*)(ws + 50 * MB);
  unsigned short* aobf  = (unsigned short*)(ws + 58 * MB);
  float*          qf32  = (float*)(ws + 66 * MB);
  float*          kf32  = (float*)(ws + 82 * MB);
  float*          vf32  = (float*)(ws + 98 * MB);
  unsigned short* vtb   = (unsigned short*)(ws + 82 * MB);  // aliases kf32: only valid AFTER qk_post(k)
  unsigned short* midbf = (unsigned short*)(ws + 66 * MB);  // aliases q/k scratch (MLP phase only)
  float* xcur = (float*)d_out;

  hipMemcpyAsync(d_out, x, (size_t)4096 * 1024 * 4, hipMemcpyDeviceToDevice, stream);

  auto cast = [&](const float* src, unsigned short* dst, int n){
    cast_kernel<<<(n / 4 + 255) / 256, 256, 0, stream>>>(src, dst, n / 4);
  };
  cast(sa_wq, wq_sa, 1024 * 1024);
  cast(sa_wk, wk_sa, 1024 * 1024);
  cast(sa_wv, wv_sa, 1024 * 1024);
  cast(sa_wo, wo_sa, 1024 * 1024);
  cast(ca_wq, wq_ca, 1024 * 1024);
  cast(ca_wk, wk_ca, 1024 * 1024);
  cast(ca_wv, wv_ca, 1024 * 1024);
  cast(ca_wo, wo_ca, 1024 * 1024);
  cast(w1, w1bf, 4096 * 1024);
  cast(w2, w2bf, 4096 * 1024);
  cast(ctx, ctxbf, 512 * 1024);
  modulation_kernel<<<2304, 256, 0, stream>>>(emb, msa, mca, mmlp, modv);

  // ---- self attention ----
  ln_mod_kernel<<<4096, 256, 0, stream>>>(xcur, modv + 0 * 3072, hbf);
  gemm_bt_kernel<0><<<dim3(8, 32), 256, 0, stream>>>(hbf, wq_sa, 4096, 1024, 1024, qf32, nullptr, nullptr, nullptr);
  gemm_bt_kernel<0><<<dim3(8, 32), 256, 0, stream>>>(hbf, wk_sa, 4096, 1024, 1024, kf32, nullptr, nullptr, nullptr);
  gemm_bt_kernel<0><<<dim3(8, 32), 256, 0, stream>>>(hbf, wv_sa, 4096, 1024, 1024, vf32, nullptr, nullptr, nullptr);
  qk_post_kernel<1><<<16384, 256, 0, stream>>>(qf32, sa_qn, rope, qbf, 4096);
  qk_post_kernel<1><<<16384, 256, 0, stream>>>(kf32, sa_kn, rope, kbf, 4096);
  vt_kernel<<<dim3(64, 16), 256, 0, stream>>>(vf32, vtb, 4096);   // after qk_post(k): overwrites kf32
  attn_kernel<<<512, 512, 0, stream>>>(qbf, kbf, vtb, aobf, 4096, 4096);
  gemm_bt_kernel<3><<<dim3(8, 32), 256, 0, stream>>>(aobf, wo_sa, 4096, 1024, 1024, xcur, nullptr, xcur, modv + 0 * 3072 + 2048);

  // ---- cross attention ----
  ln_mod_kernel<<<4096, 256, 0, stream>>>(xcur, modv + 1 * 3072, hbf);
  gemm_bt_kernel<0><<<dim3(8, 32), 256, 0, stream>>>(hbf, wq_ca, 4096, 1024, 1024, qf32, nullptr, nullptr, nullptr);
  gemm_bt_kernel<0><<<dim3(8, 4), 256, 0, stream>>>(ctxbf, wk_ca, 512, 1024, 1024, kf32, nullptr, nullptr, nullptr);
  gemm_bt_kernel<0><<<dim3(8, 4), 256, 0, stream>>>(ctxbf, wv_ca, 512, 1024, 1024, vf32, nullptr, nullptr, nullptr);
  qk_post_kernel<0><<<16384, 256, 0, stream>>>(qf32, ca_qn, nullptr, qbf, 4096);
  qk_post_kernel<0><<<2048, 256, 0, stream>>>(kf32, ca_kn, nullptr, kbf, 512);
  vt_kernel<<<dim3(8, 16), 256, 0, stream>>>(vf32, vtb, 512);     // after qk_post(k)
  attn_kernel<<<512, 512, 0, stream>>>(qbf, kbf, vtb, aobf, 4096, 512);
  gemm_bt_kernel<3><<<dim3(8, 32), 256, 0, stream>>>(aobf, wo_ca, 4096, 1024, 1024, xcur, nullptr, xcur, modv + 1 * 3072 + 2048);

  // ---- mlp ----
  ln_mod_kernel<<<4096, 256, 0, stream>>>(xcur, modv + 2 * 3072, hbf);
  gemm_bt_kernel<2><<<dim3(32, 32), 256, 0, stream>>>(hbf, w1bf, 4096, 4096, 1024, nullptr, midbf, nullptr, nullptr);
  gemm_bt_kernel<3><<<dim3(8, 32), 256, 0, stream>>>(midbf, w2bf, 4096, 1024, 4096, xcur, nullptr, xcur, modv + 2 * 3072 + 2048);
}

// Round 4
// 716.740 us; speedup vs baseline: 1.2095x; 1.2095x over previous
//
#include <hip/hip_runtime.h>
#include <hip/hip_bf16.h>

typedef __attribute__((ext_vector_type(8))) __bf16 bf16x8;
typedef __attribute__((ext_vector_type(4))) float f32x4;
typedef __attribute__((ext_vector_type(4))) unsigned short us4;

__device__ __forceinline__ unsigned short f2bf(float f){
  union { float f; unsigned int u; } a; a.f = f;
  unsigned int r = 0x7fffu + ((a.u >> 16) & 1u);
  return (unsigned short)((a.u + r) >> 16);
}

__device__ __forceinline__ void gload_lds16(const unsigned short* g, void* l){
  __builtin_amdgcn_global_load_lds(
      (const __attribute__((address_space(1))) void*)g,
      (__attribute__((address_space(3))) void*)l, 16, 0, 0);
}

// ---------------- cast fp32 -> bf16 (vector4) ----------------
__global__ __launch_bounds__(256) void cast_kernel(const float* __restrict__ in,
                                                   unsigned short* __restrict__ out, int n4){
  int i = blockIdx.x * 256 + threadIdx.x;
  if (i >= n4) return;
  float4 v = ((const float4*)in)[i];
  us4 o; o.x = f2bf(v.x); o.y = f2bf(v.y); o.z = f2bf(v.z); o.w = f2bf(v.w);
  ((us4*)out)[i] = o;
}

// ---------------- modulation: y = silu(emb) @ w.T (3 matrices of 3072x1024) ----------------
__global__ __launch_bounds__(256) void modulation_kernel(const float* __restrict__ emb,
    const float* __restrict__ w0, const float* __restrict__ w1, const float* __restrict__ w2,
    float* __restrict__ out){
  int gw = blockIdx.x * 4 + (threadIdx.x >> 6);
  int lane = threadIdx.x & 63;
  int mat = gw / 3072, row = gw % 3072;
  const float* w = (mat == 0) ? w0 : (mat == 1 ? w1 : w2);
  float acc = 0.f;
  for (int i = lane; i < 1024; i += 64){
    float e = emb[i];
    float s = e / (1.f + expf(-e));
    acc += s * w[row * 1024 + i];
  }
  #pragma unroll
  for (int m = 32; m >= 1; m >>= 1) acc += __shfl_xor(acc, m, 64);
  if (lane == 0) out[mat * 3072 + row] = acc;
}

// ---------------- layernorm * (1+scale) + shift -> bf16 ----------------
__global__ __launch_bounds__(256) void ln_mod_kernel(const float* __restrict__ x,
    const float* __restrict__ mod, unsigned short* __restrict__ h){
  int row = blockIdx.x, t = threadIdx.x;
  const float* xr = x + (size_t)row * 1024;
  float4 v = ((const float4*)xr)[t];
  float s = v.x + v.y + v.z + v.w;
  #pragma unroll
  for (int m = 32; m >= 1; m >>= 1) s += __shfl_xor(s, m, 64);
  __shared__ float red[4], red2[4];
  int wid = t >> 6, lane = t & 63;
  if (lane == 0) red[wid] = s;
  __syncthreads();
  float mean = (red[0] + red[1] + red[2] + red[3]) * (1.f / 1024.f);
  float dx = v.x - mean, dy = v.y - mean, dz = v.z - mean, dw = v.w - mean;
  float s2 = dx*dx + dy*dy + dz*dz + dw*dw;
  #pragma unroll
  for (int m = 32; m >= 1; m >>= 1) s2 += __shfl_xor(s2, m, 64);
  if (lane == 0) red2[wid] = s2;
  __syncthreads();
  float var = (red2[0] + red2[1] + red2[2] + red2[3]) * (1.f / 1024.f);
  float rs = rsqrtf(var + 1e-6f);
  int c = t * 4;
  us4 o;
  o.x = f2bf(dx * rs * (1.f + mod[1024 + c    ]) + mod[c    ]);
  o.y = f2bf(dy * rs * (1.f + mod[1024 + c + 1]) + mod[c + 1]);
  o.z = f2bf(dz * rs * (1.f + mod[1024 + c + 2]) + mod[c + 2]);
  o.w = f2bf(dw * rs * (1.f + mod[1024 + c + 3]) + mod[c + 3]);
  ((us4*)(h + (size_t)row * 1024))[t] = o;
}

// ---------------- rmsnorm (*nw) + optional rope, fp32 [S][16][64] -> bf16 [16][S][64] ----------------
template<int ROPE>
__global__ __launch_bounds__(256) void qk_post_kernel(const float* __restrict__ qin,
    const float* __restrict__ nw, const float* __restrict__ rope,
    unsigned short* __restrict__ qout, int S){
  int gw = blockIdx.x * 4 + (threadIdx.x >> 6);
  int lane = threadIdx.x & 63;
  int s = gw >> 4, h = gw & 15;
  float v = qin[(size_t)s * 1024 + h * 64 + lane];
  float ss = v * v;
  #pragma unroll
  for (int m = 32; m >= 1; m >>= 1) ss += __shfl_xor(ss, m, 64);
  float val = v * rsqrtf(ss * (1.f / 64.f) + 1e-6f) * nw[lane];
  if (ROPE){
    float partner = __shfl_xor(val, 32, 64);
    float cs = rope[s * 64 + (lane & 31)];
    float sn = rope[s * 64 + 32 + (lane & 31)];
    val = (lane < 32) ? (val * cs - partner * sn) : (val * cs + partner * sn);
  }
  qout[((size_t)h * S + s) * 64 + lane] = f2bf(val);
}

// ---------------- V transpose: fp32 [S][16][64] -> bf16 [16][64][S] ----------------
__global__ __launch_bounds__(256) void vt_kernel(const float* __restrict__ Vf,
    unsigned short* __restrict__ Vt, int S){
  int stile = blockIdx.x, h = blockIdx.y;
  __shared__ unsigned short tile[64 * 66];
  int t = threadIdx.x;
  #pragma unroll
  for (int i = 0; i < 16; i++){
    int e = i * 256 + t;
    int srow = e >> 6, d = e & 63;
    tile[d * 66 + srow] = f2bf(Vf[(size_t)(stile * 64 + srow) * 1024 + h * 64 + d]);
  }
  __syncthreads();
  #pragma unroll
  for (int i = 0; i < 16; i++){
    int e = i * 256 + t;
    int d = e >> 6, scol = e & 63;
    Vt[((size_t)h * 64 + d) * S + stile * 64 + scol] = tile[d * 66 + scol];
  }
}

// ---------------- GEMM: C[M,N] = A[M,K](bf16) * W[N,K](bf16)^T, fp32 acc ----------------
template<int EPI>
__global__ __launch_bounds__(256) void gemm_bt_kernel(
    const unsigned short* __restrict__ A, const unsigned short* __restrict__ W,
    int M, int N, int K,
    float* __restrict__ outF, unsigned short* __restrict__ outB,
    const float* __restrict__ resid, const float* __restrict__ gate){
  __shared__ short As[128 * 64];
  __shared__ short Bs[128 * 64];
  const int t = threadIdx.x, wid = t >> 6, lane = t & 63;
  const int r = lane & 15, g = lane >> 4;
  const int brow = blockIdx.y * 128, bcol = blockIdx.x * 128;
  const int wr = wid >> 1, wc = wid & 1;
  f32x4 acc[4][4] = {};
  const int nkt = K >> 6;
  for (int kt = 0; kt < nkt; ++kt){
    const int k0 = kt << 6;
    #pragma unroll
    for (int i = 0; i < 4; i++){
      int chunk = wid * 4 + i;
      int rowi = chunk * 8 + (lane >> 3);
      int lce = ((lane & 7) * 8) ^ ((rowi & 7) << 3);
      gload_lds16(A + (size_t)(brow + rowi) * K + k0 + lce, (void*)(As + chunk * 512));
      gload_lds16(W + (size_t)(bcol + rowi) * K + k0 + lce, (void*)(Bs + chunk * 512));
    }
    __syncthreads();
    #pragma unroll
    for (int kk = 0; kk < 2; kk++){
      bf16x8 af[4], bfr[4];
      #pragma unroll
      for (int m = 0; m < 4; m++){
        int ar = wr * 64 + m * 16 + r;
        af[m] = *(const bf16x8*)(As + ar * 64 + ((kk * 32 + g * 8) ^ ((ar & 7) << 3)));
      }
      #pragma unroll
      for (int n = 0; n < 4; n++){
        int br = wc * 64 + n * 16 + r;
        bfr[n] = *(const bf16x8*)(Bs + br * 64 + ((kk * 32 + g * 8) ^ ((br & 7) << 3)));
      }
      #pragma unroll
      for (int m = 0; m < 4; m++)
        #pragma unroll
        for (int n = 0; n < 4; n++)
          acc[m][n] = __builtin_amdgcn_mfma_f32_16x16x32_bf16(af[m], bfr[n], acc[m][n], 0, 0, 0);
    }
    __syncthreads();
  }
  #pragma unroll
  for (int m = 0; m < 4; m++){
    #pragma unroll
    for (int n = 0; n < 4; n++){
      int col = bcol + wc * 64 + n * 16 + r;
      #pragma unroll
      for (int j = 0; j < 4; j++){
        int rowj = brow + wr * 64 + m * 16 + g * 4 + j;
        float v = acc[m][n][j];
        if (EPI == 0){
          outF[(size_t)rowj * N + col] = v;
        } else if (EPI == 2){
          float gl = 0.5f * v * (1.f + erff(v * 0.70710678118654752f));
          outB[(size_t)rowj * N + col] = f2bf(gl);
        } else {
          outF[(size_t)rowj * N + col] = resid[(size_t)rowj * N + col] + gate[col] * v;
        }
      }
    }
  }
}

// ---------------- flash attention, KV-split x2 ----------------
// Q: bf16 [16][Sq][64], K: bf16 [16][Skv][64], Vt: bf16 [16][64][Skv], Out: bf16 [Sq][1024]
// 8 waves/block (512 thr): wave = (qsub 0..3) x (kv-half 0..1). 32 q-rows/wave.
// K/V fragments direct from global (L2-resident, XCD-aware head placement).
// After the loop: LDS flash-combine of the two halves (merge buffer aliases Ps).
// launch_bounds min-waves=2: R3's (512,4) clamped VGPR to 64 -> 789MB scratch spills.
__global__ __launch_bounds__(512, 2) void attn_kernel(
    const unsigned short* __restrict__ Qb, const unsigned short* __restrict__ Kb,
    const unsigned short* __restrict__ Vt, unsigned short* __restrict__ Out,
    int Sq, int Skv){
  __shared__ char smem[8 * 32 * 72 * 2];              // Ps (8 waves); merge region aliases it
  short* Ps = (short*)smem;
  float* mo = (float*)smem;                            // 128 rows x 64 cols f32 = 32 KB
  float* ml = (float*)(smem + 32768);                  // 128 rows x {m,l} = 1 KB
  const int t = threadIdx.x, wid = t >> 6, lane = t & 63;
  const int r = lane & 15, g = lane >> 4;
  const int qsub = wid & 3, half = wid >> 2;
  const int bid = blockIdx.x;
  const int slot = bid >> 3;
  const int h = (bid & 7) * 2 + (slot >> 5);
  const int qblk = slot & 31;
  const int qbase = qblk * 128 + qsub * 32;
  const float SC = 0.125f * 1.44269504f;               // score scale * log2(e): exp -> exp2

  bf16x8 qf[2][2];
  #pragma unroll
  for (int tile = 0; tile < 2; tile++){
    const unsigned short* qp = Qb + ((size_t)h * Sq + qbase + tile * 16 + r) * 64 + g * 8;
    qf[tile][0] = *(const bf16x8*)qp;
    qf[tile][1] = *(const bf16x8*)(qp + 32);
  }
  f32x4 o[2][4] = {};
  float mrun[2][4], lrun[2][4];
  #pragma unroll
  for (int tile = 0; tile < 2; tile++)
    #pragma unroll
    for (int j = 0; j < 4; j++){ mrun[tile][j] = -__builtin_inff(); lrun[tile][j] = 0.f; }

  const int kvHalf = Skv >> 1;
  const int kv0 = half * kvHalf;
  for (int kv = kv0; kv < kv0 + kvHalf; kv += 64){
    // ---- QK^T: K fragments direct from global ----
    const unsigned short* kp = Kb + ((size_t)h * Skv + kv + r) * 64 + g * 8;
    f32x4 sf[2][4];
    __builtin_amdgcn_s_setprio(1);
    #pragma unroll
    for (int kj = 0; kj < 4; kj++){
      bf16x8 k0 = *(const bf16x8*)(kp + kj * 1024);
      bf16x8 k1 = *(const bf16x8*)(kp + kj * 1024 + 32);
      f32x4 a0 = {}, a1 = {};
      a0 = __builtin_amdgcn_mfma_f32_16x16x32_bf16(qf[0][0], k0, a0, 0, 0, 0);
      a0 = __builtin_amdgcn_mfma_f32_16x16x32_bf16(qf[0][1], k1, a0, 0, 0, 0);
      a1 = __builtin_amdgcn_mfma_f32_16x16x32_bf16(qf[1][0], k0, a1, 0, 0, 0);
      a1 = __builtin_amdgcn_mfma_f32_16x16x32_bf16(qf[1][1], k1, a1, 0, 0, 0);
      sf[0][kj] = a0 * SC;
      sf[1][kj] = a1 * SC;
    }
    __builtin_amdgcn_s_setprio(0);
    // ---- V fragments: issue early so latency hides under softmax ----
    bf16x8 vf[2][4];
    const unsigned short* vp = Vt + ((size_t)h * 64 + r) * Skv + kv + g * 8;
    #pragma unroll
    for (int dj = 0; dj < 4; dj++){
      vf[0][dj] = *(const bf16x8*)(vp + (size_t)dj * 16 * Skv);
      vf[1][dj] = *(const bf16x8*)(vp + (size_t)dj * 16 * Skv + 32);
    }
    // ---- online softmax in exp2 domain (defer-rescale, THR=8) ----
    #pragma unroll
    for (int tile = 0; tile < 2; tile++){
      float tm[4];
      int need = 0;
      #pragma unroll
      for (int j = 0; j < 4; j++){
        float m0 = fmaxf(fmaxf(sf[tile][0][j], sf[tile][1][j]),
                         fmaxf(sf[tile][2][j], sf[tile][3][j]));
        #pragma unroll
        for (int msk = 8; msk >= 1; msk >>= 1) m0 = fmaxf(m0, __shfl_xor(m0, msk, 64));
        tm[j] = m0;
        need |= (m0 > mrun[tile][j] + 8.f) ? 1 : 0;
      }
      if (__any(need)){
        #pragma unroll
        for (int j = 0; j < 4; j++){
          float mnew = fmaxf(mrun[tile][j], tm[j]);
          float corr = exp2f(mrun[tile][j] - mnew);
          mrun[tile][j] = mnew;
          lrun[tile][j] *= corr;
          #pragma unroll
          for (int dj = 0; dj < 4; dj++) o[tile][dj][j] *= corr;
        }
      }
      #pragma unroll
      for (int j = 0; j < 4; j++){
        float rsum = 0.f;
        #pragma unroll
        for (int kj = 0; kj < 4; kj++){
          float p = exp2f(sf[tile][kj][j] - mrun[tile][j]);
          rsum += p;
          Ps[(size_t)wid * 2304 + (tile * 16 + g * 4 + j) * 72 + kj * 16 + r] = (short)f2bf(p);
        }
        #pragma unroll
        for (int msk = 8; msk >= 1; msk >>= 1) rsum += __shfl_xor(rsum, msk, 64);
        lrun[tile][j] += rsum;
      }
    }
    asm volatile("s_waitcnt lgkmcnt(0)" ::: "memory");
    // ---- PV ----
    __builtin_amdgcn_s_setprio(1);
    #pragma unroll
    for (int tile = 0; tile < 2; tile++){
      bf16x8 pf0 = *(const bf16x8*)(Ps + (size_t)wid * 2304 + (tile * 16 + r) * 72 + g * 8);
      bf16x8 pf1 = *(const bf16x8*)(Ps + (size_t)wid * 2304 + (tile * 16 + r) * 72 + 32 + g * 8);
      #pragma unroll
      for (int dj = 0; dj < 4; dj++){
        o[tile][dj] = __builtin_amdgcn_mfma_f32_16x16x32_bf16(pf0, vf[0][dj], o[tile][dj], 0, 0, 0);
        o[tile][dj] = __builtin_amdgcn_mfma_f32_16x16x32_bf16(pf1, vf[1][dj], o[tile][dj], 0, 0, 0);
      }
    }
    __builtin_amdgcn_s_setprio(0);
  }

  // ---- flash-combine the two kv halves ----
  __syncthreads();                                     // everyone done with Ps
  if (half == 1){
    #pragma unroll
    for (int tile = 0; tile < 2; tile++){
      #pragma unroll
      for (int j = 0; j < 4; j++){
        int rl = qsub * 32 + tile * 16 + g * 4 + j;
        if (r == 0){ ml[rl * 2] = mrun[tile][j]; ml[rl * 2 + 1] = lrun[tile][j]; }
        #pragma unroll
        for (int dj = 0; dj < 4; dj++) mo[rl * 64 + dj * 16 + r] = o[tile][dj][j];
      }
    }
  }
  __syncthreads();
  if (half == 0){
    #pragma unroll
    for (int tile = 0; tile < 2; tile++){
      #pragma unroll
      for (int j = 0; j < 4; j++){
        int rl = qsub * 32 + tile * 16 + g * 4 + j;
        float m1 = ml[rl * 2], l1 = ml[rl * 2 + 1];
        float m0 = mrun[tile][j], l0 = lrun[tile][j];
        float mm = fmaxf(m0, m1);
        float c0 = exp2f(m0 - mm), c1 = exp2f(m1 - mm);
        float inv = 1.f / (l0 * c0 + l1 * c1);
        int qrow = qblk * 128 + rl;
        #pragma unroll
        for (int dj = 0; dj < 4; dj++){
          float val = (o[tile][dj][j] * c0 + mo[rl * 64 + dj * 16 + r] * c1) * inv;
          Out[(size_t)qrow * 1024 + h * 64 + dj * 16 + r] = f2bf(val);
        }
      }
    }
  }
}

extern "C" void kernel_launch(void* const* d_in, const int* in_sizes, int n_in,
                              void* d_out, int out_size, void* d_ws, size_t ws_size,
                              hipStream_t stream){
  (void)n_in; (void)out_size;
  const float* x   = (const float*)d_in[0];
  const float* emb = (const float*)d_in[1];
  const float* ctx = (const float*)d_in[2];
  int wb = 3, ri = 20;
  if (in_sizes[3] == 4096 * 64) { ri = 3; wb = 4; }
  const float* rope  = (const float*)d_in[ri];
  const float* sa_wq = (const float*)d_in[wb + 0];
  const float* sa_wk = (const float*)d_in[wb + 1];
  const float* sa_wv = (const float*)d_in[wb + 2];
  const float* sa_wo = (const float*)d_in[wb + 3];
  const float* sa_qn = (const float*)d_in[wb + 4];
  const float* sa_kn = (const float*)d_in[wb + 5];
  const float* ca_wq = (const float*)d_in[wb + 6];
  const float* ca_wk = (const float*)d_in[wb + 7];
  const float* ca_wv = (const float*)d_in[wb + 8];
  const float* ca_wo = (const float*)d_in[wb + 9];
  const float* ca_qn = (const float*)d_in[wb + 10];
  const float* ca_kn = (const float*)d_in[wb + 11];
  const float* w1    = (const float*)d_in[wb + 12];
  const float* w2    = (const float*)d_in[wb + 13];
  const float* msa   = (const float*)d_in[wb + 14];
  const float* mca   = (const float*)d_in[wb + 15];
  const float* mmlp  = (const float*)d_in[wb + 16];

  char* ws = (char*)d_ws;
  const size_t MB = 1u << 20;
  if (ws_size < 114 * MB) return;
  unsigned short* wq_sa = (unsigned short*)(ws + 0 * MB);
  unsigned short* wk_sa = (unsigned short*)(ws + 2 * MB);
  unsigned short* wv_sa = (unsigned short*)(ws + 4 * MB);
  unsigned short* wo_sa = (unsigned short*)(ws + 6 * MB);
  unsigned short* wq_ca = (unsigned short*)(ws + 8 * MB);
  unsigned short* wk_ca = (unsigned short*)(ws + 10 * MB);
  unsigned short* wv_ca = (unsigned short*)(ws + 12 * MB);
  unsigned short* wo_ca = (unsigned short*)(ws + 14 * MB);
  unsigned short* w1bf  = (unsigned short*)(ws + 16 * MB);
  unsigned short* w2bf  = (unsigned short*)(ws + 24 * MB);
  unsigned short* ctxbf = (unsigned short*)(ws + 32 * MB);
  float*          modv  = (float*)(ws + 33 * MB);
  unsigned short* hbf   = (unsigned short*)(ws + 34 * MB);
  unsigned short* qbf   = (unsigned short*)(ws + 42 * MB);
  unsigned short* kbf   = (unsigned short*)(ws + 50 * MB);
  unsigned short* aobf  = (unsigned short*)(ws + 58 * MB);
  float*          qf32  = (float*)(ws + 66 * MB);
  float*          kf32  = (float*)(ws + 82 * MB);
  float*          vf32  = (float*)(ws + 98 * MB);
  unsigned short* vtb   = (unsigned short*)(ws + 82 * MB);  // aliases kf32: only valid AFTER qk_post(k)
  unsigned short* midbf = (unsigned short*)(ws + 66 * MB);  // aliases q/k scratch (MLP phase only)
  float* xcur = (float*)d_out;

  hipMemcpyAsync(d_out, x, (size_t)4096 * 1024 * 4, hipMemcpyDeviceToDevice, stream);

  auto cast = [&](const float* src, unsigned short* dst, int n){
    cast_kernel<<<(n / 4 + 255) / 256, 256, 0, stream>>>(src, dst, n / 4);
  };
  cast(sa_wq, wq_sa, 1024 * 1024);
  cast(sa_wk, wk_sa, 1024 * 1024);
  cast(sa_wv, wv_sa, 1024 * 1024);
  cast(sa_wo, wo_sa, 1024 * 1024);
  cast(ca_wq, wq_ca, 1024 * 1024);
  cast(ca_wk, wk_ca, 1024 * 1024);
  cast(ca_wv, wv_ca, 1024 * 1024);
  cast(ca_wo, wo_ca, 1024 * 1024);
  cast(w1, w1bf, 4096 * 1024);
  cast(w2, w2bf, 4096 * 1024);
  cast(ctx, ctxbf, 512 * 1024);
  modulation_kernel<<<2304, 256, 0, stream>>>(emb, msa, mca, mmlp, modv);

  // ---- self attention ----
  ln_mod_kernel<<<4096, 256, 0, stream>>>(xcur, modv + 0 * 3072, hbf);
  gemm_bt_kernel<0><<<dim3(8, 32), 256, 0, stream>>>(hbf, wq_sa, 4096, 1024, 1024, qf32, nullptr, nullptr, nullptr);
  gemm_bt_kernel<0><<<dim3(8, 32), 256, 0, stream>>>(hbf, wk_sa, 4096, 1024, 1024, kf32, nullptr, nullptr, nullptr);
  gemm_bt_kernel<0><<<dim3(8, 32), 256, 0, stream>>>(hbf, wv_sa, 4096, 1024, 1024, vf32, nullptr, nullptr, nullptr);
  qk_post_kernel<1><<<16384, 256, 0, stream>>>(qf32, sa_qn, rope, qbf, 4096);
  qk_post_kernel<1><<<16384, 256, 0, stream>>>(kf32, sa_kn, rope, kbf, 4096);
  vt_kernel<<<dim3(64, 16), 256, 0, stream>>>(vf32, vtb, 4096);   // after qk_post(k): overwrites kf32
  attn_kernel<<<512, 512, 0, stream>>>(qbf, kbf, vtb, aobf, 4096, 4096);
  gemm_bt_kernel<3><<<dim3(8, 32), 256, 0, stream>>>(aobf, wo_sa, 4096, 1024, 1024, xcur, nullptr, xcur, modv + 0 * 3072 + 2048);

  // ---- cross attention ----
  ln_mod_kernel<<<4096, 256, 0, stream>>>(xcur, modv + 1 * 3072, hbf);
  gemm_bt_kernel<0><<<dim3(8, 32), 256, 0, stream>>>(hbf, wq_ca, 4096, 1024, 1024, qf32, nullptr, nullptr, nullptr);
  gemm_bt_kernel<0><<<dim3(8, 4), 256, 0, stream>>>(ctxbf, wk_ca, 512, 1024, 1024, kf32, nullptr, nullptr, nullptr);
  gemm_bt_kernel<0><<<dim3(8, 4), 256, 0, stream>>>(ctxbf, wv_ca, 512, 1024, 1024, vf32, nullptr, nullptr, nullptr);
  qk_post_kernel<0><<<16384, 256, 0, stream>>>(qf32, ca_qn, nullptr, qbf, 4096);
  qk_post_kernel<0><<<2048, 256, 0, stream>>>(kf32, ca_kn, nullptr, kbf, 512);
  vt_kernel<<<dim3(8, 16), 256, 0, stream>>>(vf32, vtb, 512);     // after qk_post(k)
  attn_kernel<<<512, 512, 0, stream>>>(qbf, kbf, vtb, aobf, 4096, 512);
  gemm_bt_kernel<3><<<dim3(8, 32), 256, 0, stream>>>(aobf, wo_ca, 4096, 1024, 1024, xcur, nullptr, xcur, modv + 1 * 3072 + 2048);

  // ---- mlp ----
  ln_mod_kernel<<<4096, 256, 0, stream>>>(xcur, modv + 2 * 3072, hbf);
  gemm_bt_kernel<2><<<dim3(32, 32), 256, 0, stream>>>(hbf, w1bf, 4096, 4096, 1024, nullptr, midbf, nullptr, nullptr);
  gemm_bt_kernel<3><<<dim3(8, 32), 256, 0, stream>>>(midbf, w2bf, 4096, 1024, 4096, xcur, nullptr, xcur, modv + 2 * 3072 + 2048);
}

// Round 5
// 649.026 us; speedup vs baseline: 1.3357x; 1.1043x over previous
//
#include <hip/hip_runtime.h>
#include <hip/hip_bf16.h>

typedef __attribute__((ext_vector_type(8))) __bf16 bf16x8;
typedef __attribute__((ext_vector_type(4))) float f32x4;
typedef __attribute__((ext_vector_type(4))) unsigned short us4;

__device__ __forceinline__ unsigned short f2bf(float f){
  union { float f; unsigned int u; } a; a.f = f;
  unsigned int r = 0x7fffu + ((a.u >> 16) & 1u);
  return (unsigned short)((a.u + r) >> 16);
}

__device__ __forceinline__ unsigned int cvt_pk_bf16(float lo, float hi){
  unsigned int d;
  asm("v_cvt_pk_bf16_f32 %0, %1, %2" : "=v"(d) : "v"(lo), "v"(hi));
  return d;
}

__device__ __forceinline__ void gload_lds16(const unsigned short* g, void* l){
  __builtin_amdgcn_global_load_lds(
      (const __attribute__((address_space(1))) void*)g,
      (__attribute__((address_space(3))) void*)l, 16, 0, 0);
}

// ---------------- cast fp32 -> bf16 (vector4) ----------------
__global__ __launch_bounds__(256) void cast_kernel(const float* __restrict__ in,
                                                   unsigned short* __restrict__ out, int n4){
  int i = blockIdx.x * 256 + threadIdx.x;
  if (i >= n4) return;
  float4 v = ((const float4*)in)[i];
  us4 o; o.x = f2bf(v.x); o.y = f2bf(v.y); o.z = f2bf(v.z); o.w = f2bf(v.w);
  ((us4*)out)[i] = o;
}

// ---------------- modulation: y = silu(emb) @ w.T (3 matrices of 3072x1024) ----------------
__global__ __launch_bounds__(256) void modulation_kernel(const float* __restrict__ emb,
    const float* __restrict__ w0, const float* __restrict__ w1, const float* __restrict__ w2,
    float* __restrict__ out){
  int gw = blockIdx.x * 4 + (threadIdx.x >> 6);
  int lane = threadIdx.x & 63;
  int mat = gw / 3072, row = gw % 3072;
  const float* w = (mat == 0) ? w0 : (mat == 1 ? w1 : w2);
  float acc = 0.f;
  for (int i = lane; i < 1024; i += 64){
    float e = emb[i];
    float s = e / (1.f + expf(-e));
    acc += s * w[row * 1024 + i];
  }
  #pragma unroll
  for (int m = 32; m >= 1; m >>= 1) acc += __shfl_xor(acc, m, 64);
  if (lane == 0) out[mat * 3072 + row] = acc;
}

// ---------------- layernorm * (1+scale) + shift -> bf16 ----------------
__global__ __launch_bounds__(256) void ln_mod_kernel(const float* __restrict__ x,
    const float* __restrict__ mod, unsigned short* __restrict__ h){
  int row = blockIdx.x, t = threadIdx.x;
  const float* xr = x + (size_t)row * 1024;
  float4 v = ((const float4*)xr)[t];
  float s = v.x + v.y + v.z + v.w;
  #pragma unroll
  for (int m = 32; m >= 1; m >>= 1) s += __shfl_xor(s, m, 64);
  __shared__ float red[4], red2[4];
  int wid = t >> 6, lane = t & 63;
  if (lane == 0) red[wid] = s;
  __syncthreads();
  float mean = (red[0] + red[1] + red[2] + red[3]) * (1.f / 1024.f);
  float dx = v.x - mean, dy = v.y - mean, dz = v.z - mean, dw = v.w - mean;
  float s2 = dx*dx + dy*dy + dz*dz + dw*dw;
  #pragma unroll
  for (int m = 32; m >= 1; m >>= 1) s2 += __shfl_xor(s2, m, 64);
  if (lane == 0) red2[wid] = s2;
  __syncthreads();
  float var = (red2[0] + red2[1] + red2[2] + red2[3]) * (1.f / 1024.f);
  float rs = rsqrtf(var + 1e-6f);
  int c = t * 4;
  us4 o;
  o.x = f2bf(dx * rs * (1.f + mod[1024 + c    ]) + mod[c    ]);
  o.y = f2bf(dy * rs * (1.f + mod[1024 + c + 1]) + mod[c + 1]);
  o.z = f2bf(dz * rs * (1.f + mod[1024 + c + 2]) + mod[c + 2]);
  o.w = f2bf(dw * rs * (1.f + mod[1024 + c + 3]) + mod[c + 3]);
  ((us4*)(h + (size_t)row * 1024))[t] = o;
}

// ---------------- rmsnorm (*nw) + optional rope, fp32 [S][16][64] -> bf16 [16][S][64] ----------------
template<int ROPE>
__global__ __launch_bounds__(256) void qk_post_kernel(const float* __restrict__ qin,
    const float* __restrict__ nw, const float* __restrict__ rope,
    unsigned short* __restrict__ qout, int S){
  int gw = blockIdx.x * 4 + (threadIdx.x >> 6);
  int lane = threadIdx.x & 63;
  int s = gw >> 4, h = gw & 15;
  float v = qin[(size_t)s * 1024 + h * 64 + lane];
  float ss = v * v;
  #pragma unroll
  for (int m = 32; m >= 1; m >>= 1) ss += __shfl_xor(ss, m, 64);
  float val = v * rsqrtf(ss * (1.f / 64.f) + 1e-6f) * nw[lane];
  if (ROPE){
    float partner = __shfl_xor(val, 32, 64);
    float cs = rope[s * 64 + (lane & 31)];
    float sn = rope[s * 64 + 32 + (lane & 31)];
    val = (lane < 32) ? (val * cs - partner * sn) : (val * cs + partner * sn);
  }
  qout[((size_t)h * S + s) * 64 + lane] = f2bf(val);
}

// ---------------- V transpose: fp32 [S][16][64] -> bf16 [16][64][S] ----------------
__global__ __launch_bounds__(256) void vt_kernel(const float* __restrict__ Vf,
    unsigned short* __restrict__ Vt, int S){
  int stile = blockIdx.x, h = blockIdx.y;
  __shared__ unsigned short tile[64 * 66];
  int t = threadIdx.x;
  #pragma unroll
  for (int i = 0; i < 16; i++){
    int e = i * 256 + t;
    int srow = e >> 6, d = e & 63;
    tile[d * 66 + srow] = f2bf(Vf[(size_t)(stile * 64 + srow) * 1024 + h * 64 + d]);
  }
  __syncthreads();
  #pragma unroll
  for (int i = 0; i < 16; i++){
    int e = i * 256 + t;
    int d = e >> 6, scol = e & 63;
    Vt[((size_t)h * 64 + d) * S + stile * 64 + scol] = tile[d * 66 + scol];
  }
}

// ---------------- GEMM: C[M,N] = A[M,K](bf16) * W[N,K](bf16)^T, fp32 acc ----------------
// EPI: 0 = store fp32; 2 = gelu->bf16; 3 = resid + gate[col]*acc -> fp32
// EPI: 4 = split-store fp32 into buffers spaced 4M floats, each [M][1024] (fused QKV)
template<int EPI>
__global__ __launch_bounds__(256) void gemm_bt_kernel(
    const unsigned short* __restrict__ A, const unsigned short* __restrict__ W,
    int M, int N, int K,
    float* __restrict__ outF, unsigned short* __restrict__ outB,
    const float* __restrict__ resid, const float* __restrict__ gate){
  __shared__ short As[128 * 64];
  __shared__ short Bs[128 * 64];
  const int t = threadIdx.x, wid = t >> 6, lane = t & 63;
  const int r = lane & 15, g = lane >> 4;
  const int brow = blockIdx.y * 128, bcol = blockIdx.x * 128;
  const int wr = wid >> 1, wc = wid & 1;
  f32x4 acc[4][4] = {};
  const int nkt = K >> 6;
  for (int kt = 0; kt < nkt; ++kt){
    const int k0 = kt << 6;
    #pragma unroll
    for (int i = 0; i < 4; i++){
      int chunk = wid * 4 + i;
      int rowi = chunk * 8 + (lane >> 3);
      int lce = ((lane & 7) * 8) ^ ((rowi & 7) << 3);
      gload_lds16(A + (size_t)(brow + rowi) * K + k0 + lce, (void*)(As + chunk * 512));
      gload_lds16(W + (size_t)(bcol + rowi) * K + k0 + lce, (void*)(Bs + chunk * 512));
    }
    __syncthreads();
    #pragma unroll
    for (int kk = 0; kk < 2; kk++){
      bf16x8 af[4], bfr[4];
      #pragma unroll
      for (int m = 0; m < 4; m++){
        int ar = wr * 64 + m * 16 + r;
        af[m] = *(const bf16x8*)(As + ar * 64 + ((kk * 32 + g * 8) ^ ((ar & 7) << 3)));
      }
      #pragma unroll
      for (int n = 0; n < 4; n++){
        int br = wc * 64 + n * 16 + r;
        bfr[n] = *(const bf16x8*)(Bs + br * 64 + ((kk * 32 + g * 8) ^ ((br & 7) << 3)));
      }
      #pragma unroll
      for (int m = 0; m < 4; m++)
        #pragma unroll
        for (int n = 0; n < 4; n++)
          acc[m][n] = __builtin_amdgcn_mfma_f32_16x16x32_bf16(af[m], bfr[n], acc[m][n], 0, 0, 0);
    }
    __syncthreads();
  }
  #pragma unroll
  for (int m = 0; m < 4; m++){
    #pragma unroll
    for (int n = 0; n < 4; n++){
      int col = bcol + wc * 64 + n * 16 + r;
      #pragma unroll
      for (int j = 0; j < 4; j++){
        int rowj = brow + wr * 64 + m * 16 + g * 4 + j;
        float v = acc[m][n][j];
        if (EPI == 0){
          outF[(size_t)rowj * N + col] = v;
        } else if (EPI == 2){
          float gl = 0.5f * v * (1.f + erff(v * 0.70710678118654752f));
          outB[(size_t)rowj * N + col] = f2bf(gl);
        } else if (EPI == 4){
          outF[(size_t)(col >> 10) * 4194304 + (size_t)rowj * 1024 + (col & 1023)] = v;
        } else {
          outF[(size_t)rowj * N + col] = resid[(size_t)rowj * N + col] + gate[col] * v;
        }
      }
    }
  }
}

// ---------------- flash attention, swapped-QK^T in-register softmax, KV-split x2 ----------------
// Q: bf16 [16][Sq][64], K: bf16 [16][Skv][64], Vt: bf16 [16][64][Skv], Out: bf16 [Sq][1024]
// 8 waves/block (512 thr): wave = (qsub 0..3) x (kv-half 0..1). 32 q-rows/wave (2 q-tiles).
// S^T = mfma(K,Q): lane holds S[k = g*4+j (+16*kt)][q = r] -> row-reduce = in-reg tree + 2 shfl.
// P packed to bf16 via v_cvt_pk_bf16_f32, ds_write_b64, read back as PV A-fragments (b128).
// m/l state lives in q=r domain; o accumulator in q=g*4+j domain (permute on rescale/epilogue).
__global__ __launch_bounds__(512, 2) void attn_kernel(
    const unsigned short* __restrict__ Qb, const unsigned short* __restrict__ Kb,
    const unsigned short* __restrict__ Vt, unsigned short* __restrict__ Out,
    int Sq, int Skv){
  __shared__ char smem[8 * 32 * 36 * 4];               // per-wave P32 [32 q][36 dwords]; merge region aliases
  unsigned int* Pall = (unsigned int*)smem;
  float* mo = (float*)smem;                            // 128 q x 64 d f32 = 32 KB
  float* ml = (float*)(smem + 32768);                  // 128 q x {m,l} = 1 KB
  const int t = threadIdx.x, wid = t >> 6, lane = t & 63;
  const int r = lane & 15, g = lane >> 4;
  const int qsub = wid & 3, half = wid >> 2;
  const int bid = blockIdx.x;
  const int slot = bid >> 3;
  const int h = (bid & 7) * 2 + (slot >> 5);           // 2 heads/XCD -> K+V fits 4MB L2
  const int qblk = slot & 31;
  const int qbase = qblk * 128 + qsub * 32;
  unsigned int* ps = Pall + wid * (32 * 36);
  const float SC = 0.18033688f;                        // 0.125 * log2(e)
  const float THRraw = 44.361419f;                     // 8 / SC (defer-rescale threshold)

  bf16x8 qf[2][2];
  #pragma unroll
  for (int qt = 0; qt < 2; qt++){
    const unsigned short* qp = Qb + ((size_t)h * Sq + qbase + qt * 16 + r) * 64 + g * 8;
    qf[qt][0] = *(const bf16x8*)qp;
    qf[qt][1] = *(const bf16x8*)(qp + 32);
  }
  f32x4 o[2][4] = {};
  float mrun[2], lrun[2];
  mrun[0] = mrun[1] = -__builtin_inff();
  lrun[0] = lrun[1] = 0.f;

  const int kvHalf = Skv >> 1;
  const int kv0 = half * kvHalf;
  for (int kv = kv0; kv < kv0 + kvHalf; kv += 64){
    // ---- S^T = K·Q^T : K as A-operand (rows=k), Q as B-operand (rows=q) ----
    const unsigned short* kp = Kb + ((size_t)h * Skv + kv + r) * 64 + g * 8;
    f32x4 pT[2][4];
    __builtin_amdgcn_s_setprio(1);
    #pragma unroll
    for (int kt = 0; kt < 4; kt++){
      bf16x8 k0 = *(const bf16x8*)(kp + kt * 1024);
      bf16x8 k1 = *(const bf16x8*)(kp + kt * 1024 + 32);
      #pragma unroll
      for (int qt = 0; qt < 2; qt++){
        f32x4 a = {};
        a = __builtin_amdgcn_mfma_f32_16x16x32_bf16(k0, qf[qt][0], a, 0, 0, 0);
        a = __builtin_amdgcn_mfma_f32_16x16x32_bf16(k1, qf[qt][1], a, 0, 0, 0);
        pT[qt][kt] = a;
      }
    }
    __builtin_amdgcn_s_setprio(0);
    // ---- V fragments: issue early so latency hides under softmax ----
    bf16x8 vf[2][4];
    const unsigned short* vp = Vt + ((size_t)h * 64 + r) * Skv + kv + g * 8;
    #pragma unroll
    for (int dj = 0; dj < 4; dj++){
      vf[0][dj] = *(const bf16x8*)(vp + (size_t)dj * 16 * Skv);
      vf[1][dj] = *(const bf16x8*)(vp + (size_t)dj * 16 * Skv + 32);
    }
    // ---- in-register softmax: each lane owns q = r (within qt) ----
    #pragma unroll
    for (int qt = 0; qt < 2; qt++){
      f32x4 t01, t23;
      #pragma unroll
      for (int e = 0; e < 4; e++){
        t01[e] = fmaxf(pT[qt][0][e], pT[qt][1][e]);
        t23[e] = fmaxf(pT[qt][2][e], pT[qt][3][e]);
        t01[e] = fmaxf(t01[e], t23[e]);
      }
      float mm = fmaxf(fmaxf(t01[0], t01[1]), fmaxf(t01[2], t01[3]));
      mm = fmaxf(mm, __shfl_xor(mm, 16, 64));
      mm = fmaxf(mm, __shfl_xor(mm, 32, 64));
      int need = (mm > mrun[qt] + THRraw) ? 1 : 0;
      if (__any(need)){
        float mnew = fmaxf(mrun[qt], mm);
        float corr = exp2f((mrun[qt] - mnew) * SC);
        mrun[qt] = mnew;
        lrun[qt] *= corr;
        int sb = lane & 48;
        #pragma unroll
        for (int j = 0; j < 4; j++){
          float cj = __shfl(corr, sb + g * 4 + j, 64);
          #pragma unroll
          for (int dj = 0; dj < 4; dj++) o[qt][dj][j] *= cj;
        }
      }
      float msc = mrun[qt] * SC;
      unsigned int* psq = ps + (qt * 16 + r) * 36;
      f32x4 s4 = {};
      #pragma unroll
      for (int kt = 0; kt < 4; kt++){
        f32x4 pe;
        #pragma unroll
        for (int e = 0; e < 4; e++) pe[e] = exp2f(fmaf(pT[qt][kt][e], SC, -msc));
        s4 += pe;
        unsigned int w0 = cvt_pk_bf16(pe[0], pe[1]);
        unsigned int w1 = cvt_pk_bf16(pe[2], pe[3]);
        *(uint2*)(psq + kt * 8 + g * 2) = make_uint2(w0, w1);
      }
      float lsum = (s4[0] + s4[1]) + (s4[2] + s4[3]);
      lsum += __shfl_xor(lsum, 16, 64);
      lsum += __shfl_xor(lsum, 32, 64);
      lrun[qt] += lsum;
    }
    asm volatile("s_waitcnt lgkmcnt(0)" ::: "memory");
    // ---- PV: P rows (q=r, k contiguous) x V^T rows (d=r, k contiguous) ----
    __builtin_amdgcn_s_setprio(1);
    #pragma unroll
    for (int qt = 0; qt < 2; qt++){
      const unsigned int* psq = ps + (qt * 16 + r) * 36;
      bf16x8 pf0 = *(const bf16x8*)(psq + g * 4);
      bf16x8 pf1 = *(const bf16x8*)(psq + 16 + g * 4);
      #pragma unroll
      for (int dj = 0; dj < 4; dj++){
        o[qt][dj] = __builtin_amdgcn_mfma_f32_16x16x32_bf16(pf0, vf[0][dj], o[qt][dj], 0, 0, 0);
        o[qt][dj] = __builtin_amdgcn_mfma_f32_16x16x32_bf16(pf1, vf[1][dj], o[qt][dj], 0, 0, 0);
      }
    }
    __builtin_amdgcn_s_setprio(0);
  }

  // ---- flash-combine the two kv halves ----
  __syncthreads();                                     // everyone done with Ps
  const int rbase = qsub * 32;
  if (half == 1){
    #pragma unroll
    for (int qt = 0; qt < 2; qt++){
      if (g == 0){
        int rs = rbase + qt * 16 + r;
        ml[rs * 2] = mrun[qt]; ml[rs * 2 + 1] = lrun[qt];
      }
      #pragma unroll
      for (int j = 0; j < 4; j++){
        int rl = rbase + qt * 16 + g * 4 + j;
        #pragma unroll
        for (int dj = 0; dj < 4; dj++) mo[rl * 64 + dj * 16 + r] = o[qt][dj][j];
      }
    }
  }
  __syncthreads();
  if (half == 0){
    #pragma unroll
    for (int qt = 0; qt < 2; qt++){
      int rs = rbase + qt * 16 + r;
      float m1 = ml[rs * 2], l1 = ml[rs * 2 + 1];
      float m0 = mrun[qt], l0 = lrun[qt];
      float mm2 = fmaxf(m0, m1);
      float c0 = exp2f((m0 - mm2) * SC), c1 = exp2f((m1 - mm2) * SC);
      float inv = 1.f / (l0 * c0 + l1 * c1);
      float a0 = c0 * inv, a1 = c1 * inv;
      int sb = lane & 48;
      #pragma unroll
      for (int j = 0; j < 4; j++){
        float a0j = __shfl(a0, sb + g * 4 + j, 64);
        float a1j = __shfl(a1, sb + g * 4 + j, 64);
        int rl = rbase + qt * 16 + g * 4 + j;
        int qrow = qblk * 128 + rl;
        #pragma unroll
        for (int dj = 0; dj < 4; dj++){
          float val = o[qt][dj][j] * a0j + mo[rl * 64 + dj * 16 + r] * a1j;
          Out[(size_t)qrow * 1024 + h * 64 + dj * 16 + r] = f2bf(val);
        }
      }
    }
  }
}

extern "C" void kernel_launch(void* const* d_in, const int* in_sizes, int n_in,
                              void* d_out, int out_size, void* d_ws, size_t ws_size,
                              hipStream_t stream){
  (void)n_in; (void)out_size;
  const float* x   = (const float*)d_in[0];
  const float* emb = (const float*)d_in[1];
  const float* ctx = (const float*)d_in[2];
  int wb = 3, ri = 20;
  if (in_sizes[3] == 4096 * 64) { ri = 3; wb = 4; }
  const float* rope  = (const float*)d_in[ri];
  const float* sa_wq = (const float*)d_in[wb + 0];
  const float* sa_wk = (const float*)d_in[wb + 1];
  const float* sa_wv = (const float*)d_in[wb + 2];
  const float* sa_wo = (const float*)d_in[wb + 3];
  const float* sa_qn = (const float*)d_in[wb + 4];
  const float* sa_kn = (const float*)d_in[wb + 5];
  const float* ca_wq = (const float*)d_in[wb + 6];
  const float* ca_wk = (const float*)d_in[wb + 7];
  const float* ca_wv = (const float*)d_in[wb + 8];
  const float* ca_wo = (const float*)d_in[wb + 9];
  const float* ca_qn = (const float*)d_in[wb + 10];
  const float* ca_kn = (const float*)d_in[wb + 11];
  const float* w1    = (const float*)d_in[wb + 12];
  const float* w2    = (const float*)d_in[wb + 13];
  const float* msa   = (const float*)d_in[wb + 14];
  const float* mca   = (const float*)d_in[wb + 15];
  const float* mmlp  = (const float*)d_in[wb + 16];

  char* ws = (char*)d_ws;
  const size_t MB = 1u << 20;
  if (ws_size < 114 * MB) return;
  unsigned short* wq_sa = (unsigned short*)(ws + 0 * MB);   // wq|wk|wv contiguous (fused QKV)
  unsigned short* wk_sa = (unsigned short*)(ws + 2 * MB);
  unsigned short* wv_sa = (unsigned short*)(ws + 4 * MB);
  unsigned short* wo_sa = (unsigned short*)(ws + 6 * MB);
  unsigned short* wq_ca = (unsigned short*)(ws + 8 * MB);
  unsigned short* wk_ca = (unsigned short*)(ws + 10 * MB);  // wk|wv contiguous (fused ca-KV)
  unsigned short* wv_ca = (unsigned short*)(ws + 12 * MB);
  unsigned short* wo_ca = (unsigned short*)(ws + 14 * MB);
  unsigned short* w1bf  = (unsigned short*)(ws + 16 * MB);
  unsigned short* w2bf  = (unsigned short*)(ws + 24 * MB);
  unsigned short* ctxbf = (unsigned short*)(ws + 32 * MB);
  float*          modv  = (float*)(ws + 33 * MB);
  unsigned short* hbf   = (unsigned short*)(ws + 34 * MB);
  unsigned short* qbf   = (unsigned short*)(ws + 42 * MB);
  unsigned short* kbf   = (unsigned short*)(ws + 50 * MB);
  unsigned short* aobf  = (unsigned short*)(ws + 58 * MB);
  float*          qf32  = (float*)(ws + 66 * MB);           // q|k|v spaced 16MB = 4M floats (EPI=4)
  float*          kf32  = (float*)(ws + 82 * MB);
  float*          vf32  = (float*)(ws + 98 * MB);
  unsigned short* vtb   = (unsigned short*)(ws + 82 * MB);  // aliases kf32: only valid AFTER qk_post(k)
  unsigned short* midbf = (unsigned short*)(ws + 66 * MB);  // aliases q/k scratch (MLP phase only)
  float* xcur = (float*)d_out;

  hipMemcpyAsync(d_out, x, (size_t)4096 * 1024 * 4, hipMemcpyDeviceToDevice, stream);

  auto cast = [&](const float* src, unsigned short* dst, int n){
    cast_kernel<<<(n / 4 + 255) / 256, 256, 0, stream>>>(src, dst, n / 4);
  };
  cast(sa_wq, wq_sa, 1024 * 1024);
  cast(sa_wk, wk_sa, 1024 * 1024);
  cast(sa_wv, wv_sa, 1024 * 1024);
  cast(sa_wo, wo_sa, 1024 * 1024);
  cast(ca_wq, wq_ca, 1024 * 1024);
  cast(ca_wk, wk_ca, 1024 * 1024);
  cast(ca_wv, wv_ca, 1024 * 1024);
  cast(ca_wo, wo_ca, 1024 * 1024);
  cast(w1, w1bf, 4096 * 1024);
  cast(w2, w2bf, 4096 * 1024);
  cast(ctx, ctxbf, 512 * 1024);
  modulation_kernel<<<2304, 256, 0, stream>>>(emb, msa, mca, mmlp, modv);

  // ---- self attention ----
  ln_mod_kernel<<<4096, 256, 0, stream>>>(xcur, modv + 0 * 3072, hbf);
  gemm_bt_kernel<4><<<dim3(24, 32), 256, 0, stream>>>(hbf, wq_sa, 4096, 3072, 1024, qf32, nullptr, nullptr, nullptr);
  qk_post_kernel<1><<<16384, 256, 0, stream>>>(qf32, sa_qn, rope, qbf, 4096);
  qk_post_kernel<1><<<16384, 256, 0, stream>>>(kf32, sa_kn, rope, kbf, 4096);
  vt_kernel<<<dim3(64, 16), 256, 0, stream>>>(vf32, vtb, 4096);   // after qk_post(k): overwrites kf32
  attn_kernel<<<512, 512, 0, stream>>>(qbf, kbf, vtb, aobf, 4096, 4096);
  gemm_bt_kernel<3><<<dim3(8, 32), 256, 0, stream>>>(aobf, wo_sa, 4096, 1024, 1024, xcur, nullptr, xcur, modv + 0 * 3072 + 2048);

  // ---- cross attention ----
  ln_mod_kernel<<<4096, 256, 0, stream>>>(xcur, modv + 1 * 3072, hbf);
  gemm_bt_kernel<0><<<dim3(8, 32), 256, 0, stream>>>(hbf, wq_ca, 4096, 1024, 1024, qf32, nullptr, nullptr, nullptr);
  gemm_bt_kernel<4><<<dim3(16, 4), 256, 0, stream>>>(ctxbf, wk_ca, 512, 2048, 1024, kf32, nullptr, nullptr, nullptr);
  qk_post_kernel<0><<<16384, 256, 0, stream>>>(qf32, ca_qn, nullptr, qbf, 4096);
  qk_post_kernel<0><<<2048, 256, 0, stream>>>(kf32, ca_kn, nullptr, kbf, 512);
  vt_kernel<<<dim3(8, 16), 256, 0, stream>>>(vf32, vtb, 512);     // after qk_post(k)
  attn_kernel<<<512, 512, 0, stream>>>(qbf, kbf, vtb, aobf, 4096, 512);
  gemm_bt_kernel<3><<<dim3(8, 32), 256, 0, stream>>>(aobf, wo_ca, 4096, 1024, 1024, xcur, nullptr, xcur, modv + 1 * 3072 + 2048);

  // ---- mlp ----
  ln_mod_kernel<<<4096, 256, 0, stream>>>(xcur, modv + 2 * 3072, hbf);
  gemm_bt_kernel<2><<<dim3(32, 32), 256, 0, stream>>>(hbf, w1bf, 4096, 4096, 1024, nullptr, midbf, nullptr, nullptr);
  gemm_bt_kernel<3><<<dim3(8, 32), 256, 0, stream>>>(midbf, w2bf, 4096, 1024, 4096, xcur, nullptr, xcur, modv + 2 * 3072 + 2048);
}